// Round 2
// baseline (11055.112 us; speedup 1.0000x reference)
//
#include <hip/hip_runtime.h>
#include <math.h>

// GRU seq2seq on MI355X — Round 9: L2-cached h reads + acquire-invalidate.
// Theory: epoch time is dominated by streaming 32-64 MB/epoch of h data
// through the LLC via sc0sc1 (L2-bypassing) loads (~9.4 TB/s sustained).
// Fix: producers keep sc0sc1 write-through stores + flag; consumers, after
// observing the flag, issue an agent-scope acquire fence (buffer_inv -> drops
// stale clean L1/L2 lines) and then read h with PLAIN CACHED loads. The 32
// blocks of an XCD now share one L2 copy: LLC supplies each line once per
// XCD (1-2 MB/epoch), L2 fans out at 34.5 TB/s aggregate, hit latency ~200cy.
// Safety: flag polls stay sc0sc1; every yload site directly follows a
// wave_wait (fence covers it); epoch skew bounded by the per-epoch barrier;
// no dirty h lines exist (stores write-through); slot parity alternates.
// Epochs: 192+2 (enc+drains) + 48+2 (label+drains) + 336 (autoreg) = 580.

typedef _Float16 half8 __attribute__((ext_vector_type(8)));
typedef _Float16 half4f __attribute__((ext_vector_type(4)));
typedef float f32x4 __attribute__((ext_vector_type(4)));

#define DM    1024
#define TENC  192
#define TDEC  216
#define LBL   48
#define NPRED 168
#define HB    131072            // one packed h buffer: 1024*64*2 bytes
#define HE    65536             // elements per h buffer

// workspace byte offsets
// [0,4096): 32 leaf counters, 128B stride
#define OFF_H0P0 8192
#define OFF_EH10 (OFF_H0P0 + 2*HB)
#define OFF_DH1  (OFF_EH10 + 2*HB)
#define OFF_WF   (OFF_DH1 + 217*HB)
#define OFF_BF0  (OFF_WF + 3072*1024*2)

// LDS byte offsets (dynamic shared)
#define L_TA0 0                 // gh0 (Whh0)
#define L_TA1 32768             // Wf (dec only)
#define L_TB0 65536             // gi1 (Wih1)
#define L_TB1 98304             // gh1 (Whh1)
#define L_XW  131072            // xw[3][4][12] f32 = 576 B
#define L_BA  131648            // 16 f32
#define L_BAA 131712            // 16 f32
#define L_BB  131776            // 16 f32
#define L_TRA 131840            // 8 waves * 256 f32 = 8192 B
#define L_TRB 140032            // 8192 B
#define L_HSTA 148224           // 256 f16 = 512 B
#define L_HSTB 148736           // 512 B
#define SMEM_BYTES 149248

__device__ __forceinline__ float sigm(float x) { return 1.0f / (1.0f + __expf(-x)); }

// ---- device-coherent (LLC-level) accesses: bypass the non-coherent per-XCD L2.
__device__ __forceinline__ void coh_store64(void* p, unsigned long long v) {
  asm volatile("global_store_dwordx2 %0, %1, off sc0 sc1" :: "v"(p), "v"(v) : "memory");
}
__device__ __forceinline__ unsigned coh_load32(const void* p) {
  unsigned r;
  asm volatile("global_load_dword %0, %1, off sc0 sc1\n\ts_waitcnt vmcnt(0)"
               : "=v"(r) : "v"(p) : "memory");
  return r;
}
// ---- plain cached load: L1/L2-cacheable. ONLY safe after an acquire fence
// following a wave_wait (see header comment).
__device__ __forceinline__ half8 l2_load_h8(const void* p) {
  half8 r;
  asm volatile("global_load_dwordx4 %0, %1, off" : "=v"(r) : "v"(p));
  return r;
}
// drain all outstanding vmem; ties the 16 y-frags so dependent MFMAs can't hoist
__device__ __forceinline__ void ysync16(half8* y) {
  asm volatile("s_waitcnt vmcnt(0)"
               : "+v"(y[0]), "+v"(y[1]), "+v"(y[2]), "+v"(y[3]),
                 "+v"(y[4]), "+v"(y[5]), "+v"(y[6]), "+v"(y[7]),
                 "+v"(y[8]), "+v"(y[9]), "+v"(y[10]), "+v"(y[11]),
                 "+v"(y[12]), "+v"(y[13]), "+v"(y[14]), "+v"(y[15])
               :: "memory");
}

// ---- leaf-direct grid barrier. 256 blocks = 32 leaves x 8 blocks.
// Arrive: drain own stores, block-sync, one fire-and-forget leaf atomic.
__device__ __forceinline__ void bar_arrive(unsigned* leaf, int tid, int bx) {
  asm volatile("s_waitcnt vmcnt(0)" ::: "memory");   // drain our coherent stores
  __syncthreads();
  if (tid == 0)
    __hip_atomic_fetch_add(&leaf[(bx >> 3) << 5], 1u,
                           __ATOMIC_RELAXED, __HIP_MEMORY_SCOPE_AGENT);
}
// Wait (per-wave): lanes 0..15 poll the 16 leaf counters covering this
// wave's K-slice (leaf L produces kb chunk L). Release when all >= ep*8.
// On release: agent acquire fence (buffer_inv) so subsequent PLAIN loads
// can't hit stale L1/L2 lines; compiler barrier pins load placement.
__device__ __forceinline__ void wave_wait(unsigned* leaf, int lane, int kb0, unsigned ep) {
  const unsigned tgt = ep * 8u;
  const unsigned* p = &leaf[(unsigned)(kb0 + (lane & 15)) << 5];
  while (!__all((int)(coh_load32(p) >= tgt))) { }
  __builtin_amdgcn_fence(__ATOMIC_ACQUIRE, "agent");
  asm volatile("" ::: "memory");
}

// ---- LDS tile fill: pack 16 rows (row map per 4-row gate group, -1 = zeros)
// into MFMA A-fragment order: elem((kb,quad,m),j) = ((kb*64 + quad*16 + m)*8 + j)
__device__ __forceinline__ void fill_tile_f32(char* smem, int off, const float* __restrict__ src,
                                              int u0, int g0, int g1, int g2, int g3, int tid) {
  const int w = tid >> 6, lane = tid & 63;
  int gsel[4] = {g0, g1, g2, g3};
#pragma unroll
  for (int mm = 0; mm < 2; ++mm) {
    const int m = w + mm * 8;
    const int g = gsel[m >> 2];
    const long srow = (g < 0) ? -1 : (long)g * DM + u0 + (m & 3);
#pragma unroll
    for (int p = 0; p < 4; ++p) {
      const int k = p * 256 + lane * 4;
      half4f hv;
      if (srow >= 0) {
        float4 v = *(const float4*)(src + srow * DM + k);
        hv = (half4f){(_Float16)v.x, (_Float16)v.y, (_Float16)v.z, (_Float16)v.w};
      } else {
        hv = (half4f){(_Float16)0.f, (_Float16)0.f, (_Float16)0.f, (_Float16)0.f};
      }
      const int kb = k >> 5, q = (k >> 3) & 3;
      const int elem = (kb * 64 + q * 16 + m) * 8 + (k & 7);
      *(half4f*)(smem + off + elem * 2) = hv;
    }
  }
}

__device__ __forceinline__ void fill_tile_f16(char* smem, int off, const _Float16* __restrict__ src,
                                              int u0, int g0, int g1, int g2, int g3, int tid) {
  const int w = tid >> 6, lane = tid & 63;
  int gsel[4] = {g0, g1, g2, g3};
#pragma unroll
  for (int mm = 0; mm < 2; ++mm) {
    const int m = w + mm * 8;
    const int g = gsel[m >> 2];
    const long srow = (g < 0) ? -1 : (long)g * DM + u0 + (m & 3);
#pragma unroll
    for (int p = 0; p < 4; ++p) {
      const int k = p * 256 + lane * 4;
      half4f hv;
      if (srow >= 0) hv = *(const half4f*)(src + srow * DM + k);
      else hv = (half4f){(_Float16)0.f, (_Float16)0.f, (_Float16)0.f, (_Float16)0.f};
      const int kb = k >> 5, q = (k >> 3) & 3;
      const int elem = (kb * 64 + q * 16 + m) * 8 + (k & 7);
      *(half4f*)(smem + off + elem * 2) = hv;
    }
  }
}

// small per-CU constants: x-side weight slice + fused biases
__device__ __forceinline__ void fill_small(char* smem, int u0, int tid,
    const float* __restrict__ Wih0, const float* __restrict__ bihA, const float* __restrict__ bhhA,
    const float* __restrict__ bih1, const float* __restrict__ bhh1, const float* __restrict__ bf0) {
  if (tid < 132) {
    const int rr = tid / 11, c = tid - rr * 11;
    const int g = rr >> 2, ul = rr & 3;
    ((float*)(smem + L_XW))[(g * 4 + ul) * 12 + c] = Wih0[(g * DM + u0 + ul) * 11 + c];
  }
  if (tid < 4) {
    const int u = u0 + tid;
    float* bA = (float*)(smem + L_BA);
    bA[tid] = bihA[u] + bhhA[u];
    bA[4 + tid] = bihA[DM + u] + bhhA[DM + u];
    bA[8 + tid] = bhhA[2 * DM + u];
    bA[12 + tid] = bihA[2 * DM + u];
    float* bB = (float*)(smem + L_BB);
    bB[tid] = bih1[u] + bhh1[u];
    bB[4 + tid] = bih1[DM + u] + bhh1[DM + u];
    bB[8 + tid] = bhh1[2 * DM + u];
    bB[12 + tid] = bih1[2 * DM + u];
    if (bf0) {
      float* bAa = (float*)(smem + L_BAA);
      bAa[tid] = bf0[u] + bhhA[u];
      bAa[4 + tid] = bf0[DM + u] + bhhA[DM + u];
      bAa[8 + tid] = bhhA[2 * DM + u];
      bAa[12 + tid] = bf0[2 * DM + u];
    }
  }
}

#define MFMA16 __builtin_amdgcn_mfma_f32_16x16x32_f16
#define ZERO4 ((f32x4){0.f, 0.f, 0.f, 0.f})

// ---- batch-issue 16 CACHED y-fragment loads for this wave's (bs, kb0)
__device__ __forceinline__ void yload(half8* y, const _Float16* src, int kb0, int lane, int bs) {
  const half8* B = (const half8*)src + ((lane >> 4) << 6) + bs + (lane & 15);
#pragma unroll
  for (int i = 0; i < 16; ++i)
    y[i] = l2_load_h8(B + ((size_t)(kb0 + i) << 8));
}

// ---- 16-MFMA pass of one LDS tile against register-held y-frags
__device__ __forceinline__ f32x4 gemm_reg(const char* smem, int toff, int kb0, int lane,
                                          const half8* y, f32x4 seed) {
  const half8* T = (const half8*)(smem + toff);
  f32x4 aE = seed, aO = ZERO4;
#pragma unroll
  for (int i = 0; i < 16; i += 2) {
    aE = MFMA16(T[((kb0 + i) << 6) + lane], y[i], aE, 0, 0, 0);
    aO = MFMA16(T[((kb0 + i + 1) << 6) + lane], y[i + 1], aO, 0, 0, 0);
  }
  return aE + aO;
}

// ---- write acc to a TR region (all 8 waves)
__device__ __forceinline__ void tr_store(char* smem, int trOff, int w, int lane, f32x4 acc) {
  float* tr = (float*)(smem + trOff) + (w << 8);
  const int quad = lane >> 4, col = lane & 15;
  tr[(quad * 4 + 0) * 16 + col] = acc[0];
  tr[(quad * 4 + 1) * 16 + col] = acc[1];
  tr[(quad * 4 + 2) * 16 + col] = acc[2];
  tr[(quad * 4 + 3) * 16 + col] = acc[3];
}

// ---- x-side GEMV precompute. xmode 1: 7 inputs + 4 marks; 2: marks only.
__device__ __forceinline__ void x_pre(const char* smem, int xmode,
    const float* __restrict__ xin, const float* __restrict__ xmk,
    int t, int seqT, int b, int ul, float& xr, float& xz, float& xn) {
  const float* xw = (const float*)(smem + L_XW);
  xr = 0.f; xz = 0.f; xn = 0.f;
  if (xmode == 1) {
    const float* xp = xin + (size_t)(b * seqT + t) * 7;
#pragma unroll
    for (int c = 0; c < 7; ++c) {
      float v = xp[c];
      xr = fmaf(xw[ul * 12 + c], v, xr);
      xz = fmaf(xw[(4 + ul) * 12 + c], v, xz);
      xn = fmaf(xw[(8 + ul) * 12 + c], v, xn);
    }
  }
  const float* mp = xmk + (size_t)(b * seqT + t) * 4;
#pragma unroll
  for (int m = 0; m < 4; ++m) {
    float v = mp[m];
    xr = fmaf(xw[ul * 12 + 7 + m], v, xr);
    xz = fmaf(xw[(4 + ul) * 12 + 7 + m], v, xz);
    xn = fmaf(xw[(8 + ul) * 12 + 7 + m], v, xn);
  }
}

// ---- gate epilogue for one wave group (wb=0: waves0-3, wb=4: waves4-7).
__device__ __forceinline__ void epi(char* smem, int trOff, int stOff, int wb,
                                    int biasOff, float pxr, float pxz, float pxn,
                                    int tid, float& hprev) {
  const int lane = tid & 63, w = tid >> 6;
  const int bg = w - wb;
  const int col = lane & 15, ul = lane >> 4;
  const float* t0 = (const float*)(smem + trOff) + (bg << 8);
  const float* t1 = t0 + (4 << 8);
  const int b = (bg << 4) + col;
  float vr  = t0[ul * 16 + col]        + t1[ul * 16 + col];
  float vz  = t0[(4 + ul) * 16 + col]  + t1[(4 + ul) * 16 + col];
  float vnh = t0[(8 + ul) * 16 + col]  + t1[(8 + ul) * 16 + col];
  float vni = t0[(12 + ul) * 16 + col] + t1[(12 + ul) * 16 + col];
  const float* bias = (const float*)(smem + biasOff);
  float rg = sigm(vr + bias[ul] + pxr);
  float zg = sigm(vz + bias[4 + ul] + pxz);
  float ng = tanhf((vni + bias[12 + ul] + pxn) + rg * (vnh + bias[8 + ul]));
  float hn = ng + zg * (hprev - ng);
  hprev = hn;
  ((_Float16*)(smem + stOff))[b * 4 + ul] = (_Float16)hn;
}

// ---- coherent 8B store of a 512B stage region (one wave: i = 0..63)
__device__ __forceinline__ void st8(_Float16* dst, int u0, int i, const char* stage) {
  unsigned long long v = *(const unsigned long long*)(stage + i * 8);
  char* gp = (char*)dst + (((size_t)(u0 >> 3)) * 64 + i) * 16 + (size_t)(u0 & 7) * 2;
  coh_store64(gp, v);
}

// ---- prep: Wf = dW_ih0[:, :7] @ out_W (f16), bf0 = db_ih0 + dW_ih0[:, :7] @ out_b
__global__ __launch_bounds__(256) void prep_wf(const float* __restrict__ dWih0,
                                               const float* __restrict__ dbih0,
                                               const float* __restrict__ outW,
                                               const float* __restrict__ outb,
                                               char* __restrict__ ws) {
  const int j = blockIdx.x;
  _Float16* wf = (_Float16*)(ws + OFF_WF);
  float* bf0 = (float*)(ws + OFF_BF0);
  float wrow[7];
#pragma unroll
  for (int c = 0; c < 7; ++c) wrow[c] = dWih0[j * 11 + c];
#pragma unroll
  for (int p = 0; p < 4; ++p) {
    const int k = p * 256 + threadIdx.x;
    float acc = 0.f;
#pragma unroll
    for (int c = 0; c < 7; ++c) acc = fmaf(wrow[c], outW[c * DM + k], acc);
    wf[(size_t)j * DM + k] = (_Float16)acc;
  }
  if (threadIdx.x == 0) {
    float bb = dbih0[j];
#pragma unroll
    for (int c = 0; c < 7; ++c) bb = fmaf(wrow[c], outb[c], bb);
    bf0[j] = bb;
  }
}

__global__ __launch_bounds__(512) void gru_persist(
    const float* __restrict__ xe,  const float* __restrict__ xme,
    const float* __restrict__ xd,  const float* __restrict__ xmd,
    const float* __restrict__ eWih0, const float* __restrict__ eWhh0,
    const float* __restrict__ ebih0, const float* __restrict__ ebhh0,
    const float* __restrict__ eWih1, const float* __restrict__ eWhh1,
    const float* __restrict__ ebih1, const float* __restrict__ ebhh1,
    const float* __restrict__ dWih0, const float* __restrict__ dWhh0,
    const float* __restrict__ dbih0, const float* __restrict__ dbhh0,
    const float* __restrict__ dWih1, const float* __restrict__ dWhh1,
    const float* __restrict__ dbih1, const float* __restrict__ dbhh1,
    char* __restrict__ ws) {
  extern __shared__ char smem[];
  const int tid = threadIdx.x, bx = blockIdx.x;
  const int lane = tid & 63;
  const int w = tid >> 6;
  const int bg = w & 3, kslice = w >> 2;
  const int bs = bg << 4, kb0 = kslice << 4;
  const int u0 = bx << 2;
  const int bA = ((w & 3) << 4) + (lane & 15);   // epilogue batch coord
  const int ulA = lane >> 4;                      // epilogue unit coord

  unsigned* leaf = (unsigned*)ws;
  _Float16* h0p[2] = {(_Float16*)(ws + OFF_H0P0), (_Float16*)(ws + OFF_H0P0 + HB)};
  _Float16* eh1[2] = {(_Float16*)(ws + OFF_EH10), (_Float16*)(ws + OFF_EH10 + HB)};
  _Float16* dh1 = (_Float16*)(ws + OFF_DH1);
  const _Float16* wf = (const _Float16*)(ws + OFF_WF);
  const float* bf0 = (const float*)(ws + OFF_BF0);

  half8 y0[16], y1[16];
  f32x4 carryI = ZERO4, carryA = ZERO4, carryB = ZERO4;
  float pxr = 0.f, pxz = 0.f, pxn = 0.f;
  float hA = 0.f, hB = 0.f;
  unsigned ep = 0;

  // ---------- encoder weights -> LDS ----------
  fill_tile_f32(smem, L_TA0, eWhh0, u0, 0, 1, 2, -1, tid);   // gh0: r,z,nh | zeros
  fill_tile_f32(smem, L_TB0, eWih1, u0, 0, 1, -1, 2, tid);   // gi1: r,z | zeros | ni
  fill_tile_f32(smem, L_TB1, eWhh1, u0, 0, 1, 2, -1, tid);   // gh1: r,z,nh | zeros
  fill_small(smem, u0, tid, eWih0, ebih0, ebhh0, ebih1, ebhh1, nullptr);
  __syncthreads();
  if (w < 4) x_pre(smem, 1, xe, xme, 0, TENC, bA, ulA, pxr, pxz, pxn);

  // ---------- encoder: interval t = L0(t) + L1(t-2) ----------
  for (int t = 0; t < TENC; ++t) {
    wave_wait(leaf, lane, kb0, ep);
    yload(y0, h0p[t & 1], kb0, lane, bs);                       // h0(t-1)
    if (t >= 2) yload(y1, eh1[(t - 3) & 1], kb0, lane, bs);     // h1(t-3)
    ysync16(y0);
    f32x4 aA = gemm_reg(smem, L_TA0, kb0, lane, y0, ZERO4);     // gh0·h0(t-1)
    tr_store(smem, L_TRA, w, lane, aA);
    if (t >= 2) {
      f32x4 aB = gemm_reg(smem, L_TB1, kb0, lane, y1, carryI);  // + gi1·h0(t-2)
      tr_store(smem, L_TRB, w, lane, aB);
    }
    __syncthreads();
    if (w < 4) epi(smem, L_TRA, L_HSTA, 0, L_BA, pxr, pxz, pxn, tid, hA);
    else if (t >= 2) epi(smem, L_TRB, L_HSTB, 4, L_BB, 0.f, 0.f, 0.f, tid, hB);
    __syncthreads();
    if (tid < 64) st8(h0p[(t & 1) ^ 1], u0, tid, smem + L_HSTA);
    else if (t >= 2 && tid < 128) st8(eh1[t & 1], u0, tid - 64, smem + L_HSTB);
    bar_arrive(leaf, tid, bx); ++ep;
    carryI = gemm_reg(smem, L_TB0, kb0, lane, y0, ZERO4);       // gi1·h0(t-1)
    if (w < 4 && t + 1 < TENC) x_pre(smem, 1, xe, xme, t + 1, TENC, bA, ulA, pxr, pxz, pxn);
  }
  // drain E1: L1(190) -> eh1[0]
  {
    wave_wait(leaf, lane, kb0, ep);
    yload(y0, h0p[0], kb0, lane, bs);                           // h0(191)
    yload(y1, eh1[1], kb0, lane, bs);                           // h1(189)
    ysync16(y0);
    f32x4 aB = gemm_reg(smem, L_TB1, kb0, lane, y1, carryI);
    tr_store(smem, L_TRB, w, lane, aB);
    __syncthreads();
    if (w >= 4) epi(smem, L_TRB, L_HSTB, 4, L_BB, 0.f, 0.f, 0.f, tid, hB);
    __syncthreads();
    if (tid >= 64 && tid < 128) st8(eh1[0], u0, tid - 64, smem + L_HSTB);
    bar_arrive(leaf, tid, bx); ++ep;
    carryI = gemm_reg(smem, L_TB0, kb0, lane, y0, ZERO4);       // gi1·h0(191)
  }
  // drain E2: L1(191) -> dh1[0]; then swap to decoder weights
  {
    wave_wait(leaf, lane, kb0, ep);
    yload(y1, eh1[0], kb0, lane, bs);                           // h1(190)
    ysync16(y1);
    f32x4 aB = gemm_reg(smem, L_TB1, kb0, lane, y1, carryI);
    tr_store(smem, L_TRB, w, lane, aB);
    __syncthreads();
    if (w >= 4) epi(smem, L_TRB, L_HSTB, 4, L_BB, 0.f, 0.f, 0.f, tid, hB);
    __syncthreads();
    if (tid >= 64 && tid < 128) st8(dh1, u0, tid - 64, smem + L_HSTB);
    bar_arrive(leaf, tid, bx); ++ep;
    // decoder weights -> LDS (read-only globals; our own compute done)
    fill_tile_f32(smem, L_TA0, dWhh0, u0, 0, 1, 2, -1, tid);
    fill_tile_f16(smem, L_TA1, wf,    u0, 0, 1, -1, 2, tid);
    fill_tile_f32(smem, L_TB0, dWih1, u0, 0, 1, -1, 2, tid);
    fill_tile_f32(smem, L_TB1, dWhh1, u0, 0, 1, 2, -1, tid);
    fill_small(smem, u0, tid, dWih0, dbih0, dbhh0, dbih1, dbhh1, bf0);
    __syncthreads();
    if (w < 4) x_pre(smem, 1, xd, xmd, 0, TDEC, bA, ulA, pxr, pxz, pxn);
  }

  // ---------- label: interval d = L0d(d) + L1d(d-2) ----------
  for (int d = 0; d < LBL; ++d) {
    wave_wait(leaf, lane, kb0, ep);
    yload(y0, h0p[d & 1], kb0, lane, bs);                       // h0 step 192+d-1
    if (d >= 2) yload(y1, dh1 + (size_t)(d - 2) * HE, kb0, lane, bs);  // h1d(d-3)
    ysync16(y0);
    f32x4 aA = gemm_reg(smem, L_TA0, kb0, lane, y0, ZERO4);
    tr_store(smem, L_TRA, w, lane, aA);
    if (d >= 2) {
      f32x4 aB = gemm_reg(smem, L_TB1, kb0, lane, y1, carryI);
      tr_store(smem, L_TRB, w, lane, aB);
    }
    __syncthreads();
    if (w < 4) epi(smem, L_TRA, L_HSTA, 0, L_BA, pxr, pxz, pxn, tid, hA);
    else if (d >= 2) epi(smem, L_TRB, L_HSTB, 4, L_BB, 0.f, 0.f, 0.f, tid, hB);
    __syncthreads();
    if (tid < 64) st8(h0p[(d & 1) ^ 1], u0, tid, smem + L_HSTA);
    else if (d >= 2 && tid < 128) st8(dh1 + (size_t)(d - 1) * HE, u0, tid - 64, smem + L_HSTB);
    bar_arrive(leaf, tid, bx); ++ep;
    carryI = gemm_reg(smem, L_TB0, kb0, lane, y0, ZERO4);
    if (w < 4 && d + 1 < LBL) x_pre(smem, 1, xd, xmd, d + 1, TDEC, bA, ulA, pxr, pxz, pxn);
  }
  // drain D1: L1d(46) -> dh1[47]; seed carryI(gi1·h0d(47)) + carryA(gh0·h0d(47))
  {
    wave_wait(leaf, lane, kb0, ep);
    yload(y0, h0p[0], kb0, lane, bs);                           // h0d(47)
    yload(y1, dh1 + (size_t)46 * HE, kb0, lane, bs);            // h1d(45)
    ysync16(y0);
    f32x4 aB = gemm_reg(smem, L_TB1, kb0, lane, y1, carryI);
    tr_store(smem, L_TRB, w, lane, aB);
    __syncthreads();
    if (w >= 4) epi(smem, L_TRB, L_HSTB, 4, L_BB, 0.f, 0.f, 0.f, tid, hB);
    __syncthreads();
    if (tid >= 64 && tid < 128) st8(dh1 + (size_t)47 * HE, u0, tid - 64, smem + L_HSTB);
    bar_arrive(leaf, tid, bx); ++ep;
    carryI = gemm_reg(smem, L_TB0, kb0, lane, y0, ZERO4);
    carryA = gemm_reg(smem, L_TA0, kb0, lane, y0, ZERO4);
  }
  // drain D2: L1d(47) -> dh1[48]
  {
    wave_wait(leaf, lane, kb0, ep);
    yload(y1, dh1 + (size_t)47 * HE, kb0, lane, bs);
    ysync16(y1);
    f32x4 aB = gemm_reg(smem, L_TB1, kb0, lane, y1, carryI);
    tr_store(smem, L_TRB, w, lane, aB);
    __syncthreads();
    if (w >= 4) epi(smem, L_TRB, L_HSTB, 4, L_BB, 0.f, 0.f, 0.f, tid, hB);
    __syncthreads();
    if (tid >= 64 && tid < 128) st8(dh1 + (size_t)48 * HE, u0, tid - 64, smem + L_HSTB);
    bar_arrive(leaf, tid, bx); ++ep;
    if (w < 4) x_pre(smem, 2, nullptr, xmd, LBL, TDEC, bA, ulA, pxr, pxz, pxn);
  }

  // ---------- autoregressive region: s = 48..215, A/B intervals ----------
  for (int s = LBL; s < TDEC; ++s) {
    // A(s): h0(s) = f(carryA + Wf·h1(s-1) + marks); post: carryB = gh1·h1(s-1)
    wave_wait(leaf, lane, kb0, ep);
    yload(y1, dh1 + (size_t)s * HE, kb0, lane, bs);
    ysync16(y1);
    f32x4 aA = gemm_reg(smem, L_TA1, kb0, lane, y1, carryA);
    tr_store(smem, L_TRA, w, lane, aA);
    __syncthreads();
    if (w < 4) epi(smem, L_TRA, L_HSTA, 0, L_BAA, pxr, pxz, pxn, tid, hA);
    __syncthreads();
    if (tid < 64) st8(h0p[(s & 1) ^ 1], u0, tid, smem + L_HSTA);
    bar_arrive(leaf, tid, bx); ++ep;
    carryB = gemm_reg(smem, L_TB1, kb0, lane, y1, ZERO4);
    // B(s): h1(s) = f(carryB + gi1·h0(s)); post: carryA = gh0·h0(s), x_pre(s+1)
    wave_wait(leaf, lane, kb0, ep);
    yload(y0, h0p[(s & 1) ^ 1], kb0, lane, bs);
    ysync16(y0);
    f32x4 aB = gemm_reg(smem, L_TB0, kb0, lane, y0, carryB);
    tr_store(smem, L_TRB, w, lane, aB);
    __syncthreads();
    if (w >= 4) epi(smem, L_TRB, L_HSTB, 4, L_BB, 0.f, 0.f, 0.f, tid, hB);
    __syncthreads();
    if (tid >= 64 && tid < 128) st8(dh1 + (size_t)(s + 1) * HE, u0, tid - 64, smem + L_HSTB);
    bar_arrive(leaf, tid, bx); ++ep;
    carryA = gemm_reg(smem, L_TA0, kb0, lane, y0, ZERO4);
    if (w < 4 && s + 1 < TDEC) x_pre(smem, 2, nullptr, xmd, s + 1, TDEC, bA, ulA, pxr, pxz, pxn);
  }
}

// ---- epilogue projection: preds from stored h1 history (packed f16)
__global__ __launch_bounds__(64) void proj_kernel(const char* __restrict__ ws,
                                                  const float* __restrict__ outW,
                                                  const float* __restrict__ outb,
                                                  float* __restrict__ out) {
  const int ti = blockIdx.x / 7, c = blockIdx.x % 7;
  const _Float16* h = (const _Float16*)(ws + OFF_DH1) + (size_t)(LBL + 1 + ti) * HE;
  const int b = threadIdx.x;
  const float* wrow = outW + c * DM;
  float acc = outb[c];
#pragma unroll 4
  for (int k8 = 0; k8 < 128; ++k8) {
    const half8 hv = *(const half8*)(h + ((size_t)k8 * 64 + b) * 8);
    const float* wp = wrow + k8 * 8;
#pragma unroll
    for (int j = 0; j < 8; ++j) acc = fmaf((float)hv[j], wp[j], acc);
  }
  out[(size_t)b * (NPRED * 7) + ti * 7 + c] = acc;
}

extern "C" void kernel_launch(void* const* d_in, const int* in_sizes, int n_in,
                              void* d_out, int out_size, void* d_ws, size_t ws_size,
                              hipStream_t stream) {
  (void)in_sizes; (void)n_in; (void)out_size; (void)ws_size;
  const float* xe    = (const float*)d_in[0];
  const float* xme   = (const float*)d_in[1];
  const float* xd    = (const float*)d_in[2];
  const float* xmd   = (const float*)d_in[3];
  const float* eWih0 = (const float*)d_in[4];
  const float* eWhh0 = (const float*)d_in[5];
  const float* ebih0 = (const float*)d_in[6];
  const float* ebhh0 = (const float*)d_in[7];
  const float* eWih1 = (const float*)d_in[8];
  const float* eWhh1 = (const float*)d_in[9];
  const float* ebih1 = (const float*)d_in[10];
  const float* ebhh1 = (const float*)d_in[11];
  const float* dWih0 = (const float*)d_in[12];
  const float* dWhh0 = (const float*)d_in[13];
  const float* dbih0 = (const float*)d_in[14];
  const float* dbhh0 = (const float*)d_in[15];
  const float* dWih1 = (const float*)d_in[16];
  const float* dWhh1 = (const float*)d_in[17];
  const float* dbih1 = (const float*)d_in[18];
  const float* dbhh1 = (const float*)d_in[19];
  const float* outW  = (const float*)d_in[20];
  const float* outb  = (const float*)d_in[21];
  char* ws = (char*)d_ws;

  hipFuncSetAttribute(reinterpret_cast<const void*>(gru_persist),
                      hipFuncAttributeMaxDynamicSharedMemorySize, SMEM_BYTES);

  // zero: barrier counters + h0pack slot0 + encoder h1pack BOTH slots
  hipMemsetAsync(ws, 0, OFF_H0P0 + HB, stream);
  hipMemsetAsync(ws + OFF_EH10, 0, 2 * HB, stream);

  prep_wf<<<3072, 256, 0, stream>>>(dWih0, dbih0, outW, outb, ws);
  gru_persist<<<256, 512, SMEM_BYTES, stream>>>(xe, xme, xd, xmd,
                                                eWih0, eWhh0, ebih0, ebhh0,
                                                eWih1, eWhh1, ebih1, ebhh1,
                                                dWih0, dWhh0, dbih0, dbhh0,
                                                dWih1, dWhh1, dbih1, dbhh1, ws);
  proj_kernel<<<NPRED * 7, 64, 0, stream>>>(ws, outW, outb, (float*)d_out);
}

// Round 6
// 3072.930 us; speedup vs baseline: 3.5976x; 3.5976x over previous
//
#include <hip/hip_runtime.h>
#include <math.h>

// GRU seq2seq on MI355X — Round 13: R8 base + address-space burst rotation.
// R12 post-mortem: y[(j+rot)&15] runtime-indexed a register array -> scratch
// demotion (rule: runtime-indexed ext_vector arrays go to local memory) ->
// 10x+ slowdown -> watchdog abort. The rotation experiment was never run.
// R13 implements it legally: rotation lives ONLY in address arithmetic.
//  - yload: y[j] (STATIC index, stays in VGPRs) <- chunk kb0+((j+rot)&15).
//  - gemm_reg: pairs y[i] with LDS row kb0+((i+rot)&15) (runtime LDS addr,
//    which it already was). Per-block chunk-order permutation changes only
//    f32 summation order (absmax ~2.4e-4 << 1.16e-3 threshold).
//  - Purpose: all 256 blocks previously issued their 16-chunk LLC bursts in
//    identical order -> 256 simultaneous readers of the same lines. Rotation
//    by (bx & 15) spreads instantaneous same-line readership 256 -> 16.
//  - ysync16 on BOTH y arrays in dual epochs: reg-only MFMAs can hoist past
//    an asm vmcnt(0) with only a "memory" clobber; the y1 tie makes the
//    drain load-bearing now that scheduling changes.
// Epochs: 192+2 (enc+drains) + 48+2 (label+drains) + 336 (autoreg) = 580.

typedef _Float16 half8 __attribute__((ext_vector_type(8)));
typedef _Float16 half4f __attribute__((ext_vector_type(4)));
typedef float f32x4 __attribute__((ext_vector_type(4)));

#define DM    1024
#define TENC  192
#define TDEC  216
#define LBL   48
#define NPRED 168
#define HB    131072            // one packed h buffer: 1024*64*2 bytes
#define HE    65536             // elements per h buffer

// workspace byte offsets
// [0,4096): 32 leaf counters, 128B stride
#define OFF_H0P0 8192
#define OFF_EH10 (OFF_H0P0 + 2*HB)
#define OFF_DH1  (OFF_EH10 + 2*HB)
#define OFF_WF   (OFF_DH1 + 217*HB)
#define OFF_BF0  (OFF_WF + 3072*1024*2)

// LDS byte offsets (dynamic shared)
#define L_TA0 0                 // gh0 (Whh0)
#define L_TA1 32768             // Wf (dec only)
#define L_TB0 65536             // gi1 (Wih1)
#define L_TB1 98304             // gh1 (Whh1)
#define L_XW  131072            // xw[3][4][12] f32 = 576 B
#define L_BA  131648            // 16 f32
#define L_BAA 131712            // 16 f32
#define L_BB  131776            // 16 f32
#define L_TRA 131840            // 8 waves * 256 f32 = 8192 B
#define L_TRB 140032            // 8192 B
#define L_HSTA 148224           // 256 f16 = 512 B
#define L_HSTB 148736           // 512 B
#define SMEM_BYTES 149248

__device__ __forceinline__ float sigm(float x) { return 1.0f / (1.0f + __expf(-x)); }

// ---- device-coherent (LLC-level) accesses: bypass the non-coherent per-XCD L2.
__device__ __forceinline__ void coh_store64(void* p, unsigned long long v) {
  asm volatile("global_store_dwordx2 %0, %1, off sc0 sc1" :: "v"(p), "v"(v) : "memory");
}
__device__ __forceinline__ unsigned coh_load32(const void* p) {
  unsigned r;
  asm volatile("global_load_dword %0, %1, off sc0 sc1\n\ts_waitcnt vmcnt(0)"
               : "=v"(r) : "v"(p) : "memory");
  return r;
}
__device__ __forceinline__ half8 coh_load_h8(const void* p) {
  half8 r;
  asm volatile("global_load_dwordx4 %0, %1, off sc0 sc1" : "=v"(r) : "v"(p));
  return r;
}
// drain all outstanding vmem; ties the 16 y-frags so dependent MFMAs can't hoist
__device__ __forceinline__ void ysync16(half8* y) {
  asm volatile("s_waitcnt vmcnt(0)"
               : "+v"(y[0]), "+v"(y[1]), "+v"(y[2]), "+v"(y[3]),
                 "+v"(y[4]), "+v"(y[5]), "+v"(y[6]), "+v"(y[7]),
                 "+v"(y[8]), "+v"(y[9]), "+v"(y[10]), "+v"(y[11]),
                 "+v"(y[12]), "+v"(y[13]), "+v"(y[14]), "+v"(y[15])
               :: "memory");
}

// ---- leaf-direct grid barrier. 256 blocks = 32 leaves x 8 blocks.
// Arrive: drain own stores, block-sync, one fire-and-forget leaf atomic.
__device__ __forceinline__ void bar_arrive(unsigned* leaf, int tid, int bx) {
  asm volatile("s_waitcnt vmcnt(0)" ::: "memory");   // drain our coherent stores
  __syncthreads();
  if (tid == 0)
    __hip_atomic_fetch_add(&leaf[(bx >> 3) << 5], 1u,
                           __ATOMIC_RELAXED, __HIP_MEMORY_SCOPE_AGENT);
}
// Wait (per-wave): lanes 0..15 poll the 16 leaf counters covering this
// wave's K-slice (leaf L produces kb chunk L). Release when all >= ep*8.
__device__ __forceinline__ void wave_wait(unsigned* leaf, int lane, int kb0, unsigned ep) {
  const unsigned tgt = ep * 8u;
  const unsigned* p = &leaf[(unsigned)(kb0 + (lane & 15)) << 5];
  while (!__all((int)(coh_load32(p) >= tgt))) { }
}

// ---- LDS tile fill: pack 16 rows (row map per 4-row gate group, -1 = zeros)
// into MFMA A-fragment order: elem((kb,quad,m),j) = ((kb*64 + quad*16 + m)*8 + j)
__device__ __forceinline__ void fill_tile_f32(char* smem, int off, const float* __restrict__ src,
                                              int u0, int g0, int g1, int g2, int g3, int tid) {
  const int w = tid >> 6, lane = tid & 63;
  int gsel[4] = {g0, g1, g2, g3};
#pragma unroll
  for (int mm = 0; mm < 2; ++mm) {
    const int m = w + mm * 8;
    const int g = gsel[m >> 2];
    const long srow = (g < 0) ? -1 : (long)g * DM + u0 + (m & 3);
#pragma unroll
    for (int p = 0; p < 4; ++p) {
      const int k = p * 256 + lane * 4;
      half4f hv;
      if (srow >= 0) {
        float4 v = *(const float4*)(src + srow * DM + k);
        hv = (half4f){(_Float16)v.x, (_Float16)v.y, (_Float16)v.z, (_Float16)v.w};
      } else {
        hv = (half4f){(_Float16)0.f, (_Float16)0.f, (_Float16)0.f, (_Float16)0.f};
      }
      const int kb = k >> 5, q = (k >> 3) & 3;
      const int elem = (kb * 64 + q * 16 + m) * 8 + (k & 7);
      *(half4f*)(smem + off + elem * 2) = hv;
    }
  }
}

__device__ __forceinline__ void fill_tile_f16(char* smem, int off, const _Float16* __restrict__ src,
                                              int u0, int g0, int g1, int g2, int g3, int tid) {
  const int w = tid >> 6, lane = tid & 63;
  int gsel[4] = {g0, g1, g2, g3};
#pragma unroll
  for (int mm = 0; mm < 2; ++mm) {
    const int m = w + mm * 8;
    const int g = gsel[m >> 2];
    const long srow = (g < 0) ? -1 : (long)g * DM + u0 + (m & 3);
#pragma unroll
    for (int p = 0; p < 4; ++p) {
      const int k = p * 256 + lane * 4;
      half4f hv;
      if (srow >= 0) hv = *(const half4f*)(src + srow * DM + k);
      else hv = (half4f){(_Float16)0.f, (_Float16)0.f, (_Float16)0.f, (_Float16)0.f};
      const int kb = k >> 5, q = (k >> 3) & 3;
      const int elem = (kb * 64 + q * 16 + m) * 8 + (k & 7);
      *(half4f*)(smem + off + elem * 2) = hv;
    }
  }
}

// small per-CU constants: x-side weight slice + fused biases
__device__ __forceinline__ void fill_small(char* smem, int u0, int tid,
    const float* __restrict__ Wih0, const float* __restrict__ bihA, const float* __restrict__ bhhA,
    const float* __restrict__ bih1, const float* __restrict__ bhh1, const float* __restrict__ bf0) {
  if (tid < 132) {
    const int rr = tid / 11, c = tid - rr * 11;
    const int g = rr >> 2, ul = rr & 3;
    ((float*)(smem + L_XW))[(g * 4 + ul) * 12 + c] = Wih0[(g * DM + u0 + ul) * 11 + c];
  }
  if (tid < 4) {
    const int u = u0 + tid;
    float* bA = (float*)(smem + L_BA);
    bA[tid] = bihA[u] + bhhA[u];
    bA[4 + tid] = bihA[DM + u] + bhhA[DM + u];
    bA[8 + tid] = bhhA[2 * DM + u];
    bA[12 + tid] = bihA[2 * DM + u];
    float* bB = (float*)(smem + L_BB);
    bB[tid] = bih1[u] + bhh1[u];
    bB[4 + tid] = bih1[DM + u] + bhh1[DM + u];
    bB[8 + tid] = bhh1[2 * DM + u];
    bB[12 + tid] = bih1[2 * DM + u];
    if (bf0) {
      float* bAa = (float*)(smem + L_BAA);
      bAa[tid] = bf0[u] + bhhA[u];
      bAa[4 + tid] = bf0[DM + u] + bhhA[DM + u];
      bAa[8 + tid] = bhhA[2 * DM + u];
      bAa[12 + tid] = bf0[2 * DM + u];
    }
  }
}

#define MFMA16 __builtin_amdgcn_mfma_f32_16x16x32_f16
#define ZERO4 ((f32x4){0.f, 0.f, 0.f, 0.f})

// ---- batch-issue 16 coherent y-fragment loads for this wave's (bs, kb0).
// Register index j is STATIC (y stays in VGPRs); the rotation lives in the
// address: y[j] holds chunk kb0 + ((j+rot)&15). gemm_reg uses the same map.
__device__ __forceinline__ void yload(half8* y, const _Float16* src, int kb0, int lane, int bs, int rot) {
  const half8* B = (const half8*)src + ((lane >> 4) << 6) + bs + (lane & 15);
#pragma unroll
  for (int j = 0; j < 16; ++j)
    y[j] = coh_load_h8(B + ((size_t)(kb0 + ((j + rot) & 15)) << 8));
}

// ---- 16-MFMA pass of one LDS tile against register-held y-frags.
// y[i] holds chunk kb0+((i+rot)&15); pair it with the matching LDS A-row.
__device__ __forceinline__ f32x4 gemm_reg(const char* smem, int toff, int kb0, int lane,
                                          const half8* y, f32x4 seed, int rot) {
  const half8* T = (const half8*)(smem + toff);
  f32x4 aE = seed, aO = ZERO4;
#pragma unroll
  for (int i = 0; i < 16; i += 2) {
    aE = MFMA16(T[((kb0 + ((i + rot) & 15)) << 6) + lane], y[i], aE, 0, 0, 0);
    aO = MFMA16(T[((kb0 + ((i + 1 + rot) & 15)) << 6) + lane], y[i + 1], aO, 0, 0, 0);
  }
  return aE + aO;
}

// ---- write acc to a TR region (all 8 waves)
__device__ __forceinline__ void tr_store(char* smem, int trOff, int w, int lane, f32x4 acc) {
  float* tr = (float*)(smem + trOff) + (w << 8);
  const int quad = lane >> 4, col = lane & 15;
  tr[(quad * 4 + 0) * 16 + col] = acc[0];
  tr[(quad * 4 + 1) * 16 + col] = acc[1];
  tr[(quad * 4 + 2) * 16 + col] = acc[2];
  tr[(quad * 4 + 3) * 16 + col] = acc[3];
}

// ---- x-side GEMV precompute. xmode 1: 7 inputs + 4 marks; 2: marks only.
__device__ __forceinline__ void x_pre(const char* smem, int xmode,
    const float* __restrict__ xin, const float* __restrict__ xmk,
    int t, int seqT, int b, int ul, float& xr, float& xz, float& xn) {
  const float* xw = (const float*)(smem + L_XW);
  xr = 0.f; xz = 0.f; xn = 0.f;
  if (xmode == 1) {
    const float* xp = xin + (size_t)(b * seqT + t) * 7;
#pragma unroll
    for (int c = 0; c < 7; ++c) {
      float v = xp[c];
      xr = fmaf(xw[ul * 12 + c], v, xr);
      xz = fmaf(xw[(4 + ul) * 12 + c], v, xz);
      xn = fmaf(xw[(8 + ul) * 12 + c], v, xn);
    }
  }
  const float* mp = xmk + (size_t)(b * seqT + t) * 4;
#pragma unroll
  for (int m = 0; m < 4; ++m) {
    float v = mp[m];
    xr = fmaf(xw[ul * 12 + 7 + m], v, xr);
    xz = fmaf(xw[(4 + ul) * 12 + 7 + m], v, xz);
    xn = fmaf(xw[(8 + ul) * 12 + 7 + m], v, xn);
  }
}

// ---- gate epilogue for one wave group (wb=0: waves0-3, wb=4: waves4-7).
__device__ __forceinline__ void epi(char* smem, int trOff, int stOff, int wb,
                                    int biasOff, float pxr, float pxz, float pxn,
                                    int tid, float& hprev) {
  const int lane = tid & 63, w = tid >> 6;
  const int bg = w - wb;
  const int col = lane & 15, ul = lane >> 4;
  const float* t0 = (const float*)(smem + trOff) + (bg << 8);
  const float* t1 = t0 + (4 << 8);
  const int b = (bg << 4) + col;
  float vr  = t0[ul * 16 + col]        + t1[ul * 16 + col];
  float vz  = t0[(4 + ul) * 16 + col]  + t1[(4 + ul) * 16 + col];
  float vnh = t0[(8 + ul) * 16 + col]  + t1[(8 + ul) * 16 + col];
  float vni = t0[(12 + ul) * 16 + col] + t1[(12 + ul) * 16 + col];
  const float* bias = (const float*)(smem + biasOff);
  float rg = sigm(vr + bias[ul] + pxr);
  float zg = sigm(vz + bias[4 + ul] + pxz);
  float ng = tanhf((vni + bias[12 + ul] + pxn) + rg * (vnh + bias[8 + ul]));
  float hn = ng + zg * (hprev - ng);
  hprev = hn;
  ((_Float16*)(smem + stOff))[b * 4 + ul] = (_Float16)hn;
}

// ---- coherent 8B store of a 512B stage region (one wave: i = 0..63)
__device__ __forceinline__ void st8(_Float16* dst, int u0, int i, const char* stage) {
  unsigned long long v = *(const unsigned long long*)(stage + i * 8);
  char* gp = (char*)dst + (((size_t)(u0 >> 3)) * 64 + i) * 16 + (size_t)(u0 & 7) * 2;
  coh_store64(gp, v);
}

// ---- prep: Wf = dW_ih0[:, :7] @ out_W (f16), bf0 = db_ih0 + dW_ih0[:, :7] @ out_b
__global__ __launch_bounds__(256) void prep_wf(const float* __restrict__ dWih0,
                                               const float* __restrict__ dbih0,
                                               const float* __restrict__ outW,
                                               const float* __restrict__ outb,
                                               char* __restrict__ ws) {
  const int j = blockIdx.x;
  _Float16* wf = (_Float16*)(ws + OFF_WF);
  float* bf0 = (float*)(ws + OFF_BF0);
  float wrow[7];
#pragma unroll
  for (int c = 0; c < 7; ++c) wrow[c] = dWih0[j * 11 + c];
#pragma unroll
  for (int p = 0; p < 4; ++p) {
    const int k = p * 256 + threadIdx.x;
    float acc = 0.f;
#pragma unroll
    for (int c = 0; c < 7; ++c) acc = fmaf(wrow[c], outW[c * DM + k], acc);
    wf[(size_t)j * DM + k] = (_Float16)acc;
  }
  if (threadIdx.x == 0) {
    float bb = dbih0[j];
#pragma unroll
    for (int c = 0; c < 7; ++c) bb = fmaf(wrow[c], outb[c], bb);
    bf0[j] = bb;
  }
}

__global__ __launch_bounds__(512) void gru_persist(
    const float* __restrict__ xe,  const float* __restrict__ xme,
    const float* __restrict__ xd,  const float* __restrict__ xmd,
    const float* __restrict__ eWih0, const float* __restrict__ eWhh0,
    const float* __restrict__ ebih0, const float* __restrict__ ebhh0,
    const float* __restrict__ eWih1, const float* __restrict__ eWhh1,
    const float* __restrict__ ebih1, const float* __restrict__ ebhh1,
    const float* __restrict__ dWih0, const float* __restrict__ dWhh0,
    const float* __restrict__ dbih0, const float* __restrict__ dbhh0,
    const float* __restrict__ dWih1, const float* __restrict__ dWhh1,
    const float* __restrict__ dbih1, const float* __restrict__ dbhh1,
    char* __restrict__ ws) {
  extern __shared__ char smem[];
  const int tid = threadIdx.x, bx = blockIdx.x;
  const int lane = tid & 63;
  const int w = tid >> 6;
  const int bg = w & 3, kslice = w >> 2;
  const int bs = bg << 4, kb0 = kslice << 4;
  const int u0 = bx << 2;
  const int rot = bx & 15;                        // LLC burst rotation (addr-only)
  const int bA = ((w & 3) << 4) + (lane & 15);   // epilogue batch coord
  const int ulA = lane >> 4;                      // epilogue unit coord

  unsigned* leaf = (unsigned*)ws;
  _Float16* h0p[2] = {(_Float16*)(ws + OFF_H0P0), (_Float16*)(ws + OFF_H0P0 + HB)};
  _Float16* eh1[2] = {(_Float16*)(ws + OFF_EH10), (_Float16*)(ws + OFF_EH10 + HB)};
  _Float16* dh1 = (_Float16*)(ws + OFF_DH1);
  const _Float16* wf = (const _Float16*)(ws + OFF_WF);
  const float* bf0 = (const float*)(ws + OFF_BF0);

  half8 y0[16], y1[16];
  f32x4 carryI = ZERO4, carryA = ZERO4, carryB = ZERO4;
  float pxr = 0.f, pxz = 0.f, pxn = 0.f;
  float hA = 0.f, hB = 0.f;
  unsigned ep = 0;

  // ---------- encoder weights -> LDS ----------
  fill_tile_f32(smem, L_TA0, eWhh0, u0, 0, 1, 2, -1, tid);   // gh0: r,z,nh | zeros
  fill_tile_f32(smem, L_TB0, eWih1, u0, 0, 1, -1, 2, tid);   // gi1: r,z | zeros | ni
  fill_tile_f32(smem, L_TB1, eWhh1, u0, 0, 1, 2, -1, tid);   // gh1: r,z,nh | zeros
  fill_small(smem, u0, tid, eWih0, ebih0, ebhh0, ebih1, ebhh1, nullptr);
  __syncthreads();
  if (w < 4) x_pre(smem, 1, xe, xme, 0, TENC, bA, ulA, pxr, pxz, pxn);

  // ---------- encoder: interval t = L0(t) + L1(t-2) ----------
  for (int t = 0; t < TENC; ++t) {
    wave_wait(leaf, lane, kb0, ep);
    yload(y0, h0p[t & 1], kb0, lane, bs, rot);                  // h0(t-1)
    if (t >= 2) yload(y1, eh1[(t - 3) & 1], kb0, lane, bs, rot); // h1(t-3)
    ysync16(y0);
    if (t >= 2) ysync16(y1);
    f32x4 aA = gemm_reg(smem, L_TA0, kb0, lane, y0, ZERO4, rot); // gh0·h0(t-1)
    tr_store(smem, L_TRA, w, lane, aA);
    if (t >= 2) {
      f32x4 aB = gemm_reg(smem, L_TB1, kb0, lane, y1, carryI, rot); // + gi1·h0(t-2)
      tr_store(smem, L_TRB, w, lane, aB);
    }
    __syncthreads();
    if (w < 4) epi(smem, L_TRA, L_HSTA, 0, L_BA, pxr, pxz, pxn, tid, hA);
    else if (t >= 2) epi(smem, L_TRB, L_HSTB, 4, L_BB, 0.f, 0.f, 0.f, tid, hB);
    __syncthreads();
    if (tid < 64) st8(h0p[(t & 1) ^ 1], u0, tid, smem + L_HSTA);
    else if (t >= 2 && tid < 128) st8(eh1[t & 1], u0, tid - 64, smem + L_HSTB);
    bar_arrive(leaf, tid, bx); ++ep;
    carryI = gemm_reg(smem, L_TB0, kb0, lane, y0, ZERO4, rot);   // gi1·h0(t-1)
    if (w < 4 && t + 1 < TENC) x_pre(smem, 1, xe, xme, t + 1, TENC, bA, ulA, pxr, pxz, pxn);
  }
  // drain E1: L1(190) -> eh1[0]
  {
    wave_wait(leaf, lane, kb0, ep);
    yload(y0, h0p[0], kb0, lane, bs, rot);                      // h0(191)
    yload(y1, eh1[1], kb0, lane, bs, rot);                      // h1(189)
    ysync16(y0);
    ysync16(y1);
    f32x4 aB = gemm_reg(smem, L_TB1, kb0, lane, y1, carryI, rot);
    tr_store(smem, L_TRB, w, lane, aB);
    __syncthreads();
    if (w >= 4) epi(smem, L_TRB, L_HSTB, 4, L_BB, 0.f, 0.f, 0.f, tid, hB);
    __syncthreads();
    if (tid >= 64 && tid < 128) st8(eh1[0], u0, tid - 64, smem + L_HSTB);
    bar_arrive(leaf, tid, bx); ++ep;
    carryI = gemm_reg(smem, L_TB0, kb0, lane, y0, ZERO4, rot);   // gi1·h0(191)
  }
  // drain E2: L1(191) -> dh1[0]; then swap to decoder weights
  {
    wave_wait(leaf, lane, kb0, ep);
    yload(y1, eh1[0], kb0, lane, bs, rot);                      // h1(190)
    ysync16(y1);
    f32x4 aB = gemm_reg(smem, L_TB1, kb0, lane, y1, carryI, rot);
    tr_store(smem, L_TRB, w, lane, aB);
    __syncthreads();
    if (w >= 4) epi(smem, L_TRB, L_HSTB, 4, L_BB, 0.f, 0.f, 0.f, tid, hB);
    __syncthreads();
    if (tid >= 64 && tid < 128) st8(dh1, u0, tid - 64, smem + L_HSTB);
    bar_arrive(leaf, tid, bx); ++ep;
    // decoder weights -> LDS (read-only globals; our own compute done)
    fill_tile_f32(smem, L_TA0, dWhh0, u0, 0, 1, 2, -1, tid);
    fill_tile_f16(smem, L_TA1, wf,    u0, 0, 1, -1, 2, tid);
    fill_tile_f32(smem, L_TB0, dWih1, u0, 0, 1, -1, 2, tid);
    fill_tile_f32(smem, L_TB1, dWhh1, u0, 0, 1, 2, -1, tid);
    fill_small(smem, u0, tid, dWih0, dbih0, dbhh0, dbih1, dbhh1, bf0);
    __syncthreads();
    if (w < 4) x_pre(smem, 1, xd, xmd, 0, TDEC, bA, ulA, pxr, pxz, pxn);
  }

  // ---------- label: interval d = L0d(d) + L1d(d-2) ----------
  for (int d = 0; d < LBL; ++d) {
    wave_wait(leaf, lane, kb0, ep);
    yload(y0, h0p[d & 1], kb0, lane, bs, rot);                  // h0 step 192+d-1
    if (d >= 2) yload(y1, dh1 + (size_t)(d - 2) * HE, kb0, lane, bs, rot);  // h1d(d-3)
    ysync16(y0);
    if (d >= 2) ysync16(y1);
    f32x4 aA = gemm_reg(smem, L_TA0, kb0, lane, y0, ZERO4, rot);
    tr_store(smem, L_TRA, w, lane, aA);
    if (d >= 2) {
      f32x4 aB = gemm_reg(smem, L_TB1, kb0, lane, y1, carryI, rot);
      tr_store(smem, L_TRB, w, lane, aB);
    }
    __syncthreads();
    if (w < 4) epi(smem, L_TRA, L_HSTA, 0, L_BA, pxr, pxz, pxn, tid, hA);
    else if (d >= 2) epi(smem, L_TRB, L_HSTB, 4, L_BB, 0.f, 0.f, 0.f, tid, hB);
    __syncthreads();
    if (tid < 64) st8(h0p[(d & 1) ^ 1], u0, tid, smem + L_HSTA);
    else if (d >= 2 && tid < 128) st8(dh1 + (size_t)(d - 1) * HE, u0, tid - 64, smem + L_HSTB);
    bar_arrive(leaf, tid, bx); ++ep;
    carryI = gemm_reg(smem, L_TB0, kb0, lane, y0, ZERO4, rot);
    if (w < 4 && d + 1 < LBL) x_pre(smem, 1, xd, xmd, d + 1, TDEC, bA, ulA, pxr, pxz, pxn);
  }
  // drain D1: L1d(46) -> dh1[47]; seed carryI(gi1·h0d(47)) + carryA(gh0·h0d(47))
  {
    wave_wait(leaf, lane, kb0, ep);
    yload(y0, h0p[0], kb0, lane, bs, rot);                      // h0d(47)
    yload(y1, dh1 + (size_t)46 * HE, kb0, lane, bs, rot);       // h1d(45)
    ysync16(y0);
    ysync16(y1);
    f32x4 aB = gemm_reg(smem, L_TB1, kb0, lane, y1, carryI, rot);
    tr_store(smem, L_TRB, w, lane, aB);
    __syncthreads();
    if (w >= 4) epi(smem, L_TRB, L_HSTB, 4, L_BB, 0.f, 0.f, 0.f, tid, hB);
    __syncthreads();
    if (tid >= 64 && tid < 128) st8(dh1 + (size_t)47 * HE, u0, tid - 64, smem + L_HSTB);
    bar_arrive(leaf, tid, bx); ++ep;
    carryI = gemm_reg(smem, L_TB0, kb0, lane, y0, ZERO4, rot);
    carryA = gemm_reg(smem, L_TA0, kb0, lane, y0, ZERO4, rot);
  }
  // drain D2: L1d(47) -> dh1[48]
  {
    wave_wait(leaf, lane, kb0, ep);
    yload(y1, dh1 + (size_t)47 * HE, kb0, lane, bs, rot);
    ysync16(y1);
    f32x4 aB = gemm_reg(smem, L_TB1, kb0, lane, y1, carryI, rot);
    tr_store(smem, L_TRB, w, lane, aB);
    __syncthreads();
    if (w >= 4) epi(smem, L_TRB, L_HSTB, 4, L_BB, 0.f, 0.f, 0.f, tid, hB);
    __syncthreads();
    if (tid >= 64 && tid < 128) st8(dh1 + (size_t)48 * HE, u0, tid - 64, smem + L_HSTB);
    bar_arrive(leaf, tid, bx); ++ep;
    if (w < 4) x_pre(smem, 2, nullptr, xmd, LBL, TDEC, bA, ulA, pxr, pxz, pxn);
  }

  // ---------- autoregressive region: s = 48..215, A/B intervals ----------
  for (int s = LBL; s < TDEC; ++s) {
    // A(s): h0(s) = f(carryA + Wf·h1(s-1) + marks); post: carryB = gh1·h1(s-1)
    wave_wait(leaf, lane, kb0, ep);
    yload(y1, dh1 + (size_t)s * HE, kb0, lane, bs, rot);
    ysync16(y1);
    f32x4 aA = gemm_reg(smem, L_TA1, kb0, lane, y1, carryA, rot);
    tr_store(smem, L_TRA, w, lane, aA);
    __syncthreads();
    if (w < 4) epi(smem, L_TRA, L_HSTA, 0, L_BAA, pxr, pxz, pxn, tid, hA);
    __syncthreads();
    if (tid < 64) st8(h0p[(s & 1) ^ 1], u0, tid, smem + L_HSTA);
    bar_arrive(leaf, tid, bx); ++ep;
    carryB = gemm_reg(smem, L_TB1, kb0, lane, y1, ZERO4, rot);
    // B(s): h1(s) = f(carryB + gi1·h0(s)); post: carryA = gh0·h0(s), x_pre(s+1)
    wave_wait(leaf, lane, kb0, ep);
    yload(y0, h0p[(s & 1) ^ 1], kb0, lane, bs, rot);
    ysync16(y0);
    f32x4 aB = gemm_reg(smem, L_TB0, kb0, lane, y0, carryB, rot);
    tr_store(smem, L_TRB, w, lane, aB);
    __syncthreads();
    if (w >= 4) epi(smem, L_TRB, L_HSTB, 4, L_BB, 0.f, 0.f, 0.f, tid, hB);
    __syncthreads();
    if (tid >= 64 && tid < 128) st8(dh1 + (size_t)(s + 1) * HE, u0, tid - 64, smem + L_HSTB);
    bar_arrive(leaf, tid, bx); ++ep;
    carryA = gemm_reg(smem, L_TA0, kb0, lane, y0, ZERO4, rot);
    if (w < 4 && s + 1 < TDEC) x_pre(smem, 2, nullptr, xmd, s + 1, TDEC, bA, ulA, pxr, pxz, pxn);
  }
}

// ---- epilogue projection: preds from stored h1 history (packed f16)
__global__ __launch_bounds__(64) void proj_kernel(const char* __restrict__ ws,
                                                  const float* __restrict__ outW,
                                                  const float* __restrict__ outb,
                                                  float* __restrict__ out) {
  const int ti = blockIdx.x / 7, c = blockIdx.x % 7;
  const _Float16* h = (const _Float16*)(ws + OFF_DH1) + (size_t)(LBL + 1 + ti) * HE;
  const int b = threadIdx.x;
  const float* wrow = outW + c * DM;
  float acc = outb[c];
#pragma unroll 4
  for (int k8 = 0; k8 < 128; ++k8) {
    const half8 hv = *(const half8*)(h + ((size_t)k8 * 64 + b) * 8);
    const float* wp = wrow + k8 * 8;
#pragma unroll
    for (int j = 0; j < 8; ++j) acc = fmaf((float)hv[j], wp[j], acc);
  }
  out[(size_t)b * (NPRED * 7) + ti * 7 + c] = acc;
}

extern "C" void kernel_launch(void* const* d_in, const int* in_sizes, int n_in,
                              void* d_out, int out_size, void* d_ws, size_t ws_size,
                              hipStream_t stream) {
  (void)in_sizes; (void)n_in; (void)out_size; (void)ws_size;
  const float* xe    = (const float*)d_in[0];
  const float* xme   = (const float*)d_in[1];
  const float* xd    = (const float*)d_in[2];
  const float* xmd   = (const float*)d_in[3];
  const float* eWih0 = (const float*)d_in[4];
  const float* eWhh0 = (const float*)d_in[5];
  const float* ebih0 = (const float*)d_in[6];
  const float* ebhh0 = (const float*)d_in[7];
  const float* eWih1 = (const float*)d_in[8];
  const float* eWhh1 = (const float*)d_in[9];
  const float* ebih1 = (const float*)d_in[10];
  const float* ebhh1 = (const float*)d_in[11];
  const float* dWih0 = (const float*)d_in[12];
  const float* dWhh0 = (const float*)d_in[13];
  const float* dbih0 = (const float*)d_in[14];
  const float* dbhh0 = (const float*)d_in[15];
  const float* dWih1 = (const float*)d_in[16];
  const float* dWhh1 = (const float*)d_in[17];
  const float* dbih1 = (const float*)d_in[18];
  const float* dbhh1 = (const float*)d_in[19];
  const float* outW  = (const float*)d_in[20];
  const float* outb  = (const float*)d_in[21];
  char* ws = (char*)d_ws;

  hipFuncSetAttribute(reinterpret_cast<const void*>(gru_persist),
                      hipFuncAttributeMaxDynamicSharedMemorySize, SMEM_BYTES);

  // zero: barrier counters + h0pack slot0 + encoder h1pack BOTH slots
  hipMemsetAsync(ws, 0, OFF_H0P0 + HB, stream);
  hipMemsetAsync(ws + OFF_EH10, 0, 2 * HB, stream);

  prep_wf<<<3072, 256, 0, stream>>>(dWih0, dbih0, outW, outb, ws);
  gru_persist<<<256, 512, SMEM_BYTES, stream>>>(xe, xme, xd, xmd,
                                                eWih0, eWhh0, ebih0, ebhh0,
                                                eWih1, eWhh1, ebih1, ebhh1,
                                                dWih0, dWhh0, dbih0, dbhh0,
                                                dWih1, dWhh1, dbih1, dbhh1, ws);
  proj_kernel<<<NPRED * 7, 64, 0, stream>>>(ws, outW, outb, (float*)d_out);
}

// Round 7
// 2815.816 us; speedup vs baseline: 3.9261x; 1.0913x over previous
//
#include <hip/hip_runtime.h>
#include <math.h>

// GRU seq2seq on MI355X — Round 14: R8 base + poll-decay + backoff.
// R13 post-mortem: burst rotation REGRESSED 9% (runtime rot addressing in the
// MFMA loop; LLC handles concurrent same-line reads fine). Reverted to the
// verified R8 data path (2816us). This round attacks the FLAG-POLL STORM:
// during each epoch's wait, ~2048 waves each re-load 16 flag addresses every
// ~700cy (vmcnt-serialized) => ~45-50 LLC req/cy concentrated on 32 lines,
// contending with the 32-64MB data streams of blocks already past their wait.
// Changes (poll path only, data path byte-identical to R8):
//  (1) poll decay: lanes latch success and stop re-loading passed flags.
//  (2) s_sleep(2) backoff after each failed ballot (~128cy; negligible
//      release-latency cost, cuts steady-state poll rate).
//  (3) ytie16(y1): zero-instruction volatile register tie after the vmcnt(0)
//      drain so y1-consuming MFMAs cannot hoist above it (latent hazard fix;
//      no second waitcnt, no runtime addressing).
// Epochs: 192+2 (enc+drains) + 48+2 (label+drains) + 336 (autoreg) = 580.

typedef _Float16 half8 __attribute__((ext_vector_type(8)));
typedef _Float16 half4f __attribute__((ext_vector_type(4)));
typedef float f32x4 __attribute__((ext_vector_type(4)));

#define DM    1024
#define TENC  192
#define TDEC  216
#define LBL   48
#define NPRED 168
#define HB    131072            // one packed h buffer: 1024*64*2 bytes
#define HE    65536             // elements per h buffer

// workspace byte offsets
// [0,4096): 32 leaf counters, 128B stride
#define OFF_H0P0 8192
#define OFF_EH10 (OFF_H0P0 + 2*HB)
#define OFF_DH1  (OFF_EH10 + 2*HB)
#define OFF_WF   (OFF_DH1 + 217*HB)
#define OFF_BF0  (OFF_WF + 3072*1024*2)

// LDS byte offsets (dynamic shared)
#define L_TA0 0                 // gh0 (Whh0)
#define L_TA1 32768             // Wf (dec only)
#define L_TB0 65536             // gi1 (Wih1)
#define L_TB1 98304             // gh1 (Whh1)
#define L_XW  131072            // xw[3][4][12] f32 = 576 B
#define L_BA  131648            // 16 f32
#define L_BAA 131712            // 16 f32
#define L_BB  131776            // 16 f32
#define L_TRA 131840            // 8 waves * 256 f32 = 8192 B
#define L_TRB 140032            // 8192 B
#define L_HSTA 148224           // 256 f16 = 512 B
#define L_HSTB 148736           // 512 B
#define SMEM_BYTES 149248

__device__ __forceinline__ float sigm(float x) { return 1.0f / (1.0f + __expf(-x)); }

// ---- device-coherent (LLC-level) accesses: bypass the non-coherent per-XCD L2.
__device__ __forceinline__ void coh_store64(void* p, unsigned long long v) {
  asm volatile("global_store_dwordx2 %0, %1, off sc0 sc1" :: "v"(p), "v"(v) : "memory");
}
__device__ __forceinline__ unsigned coh_load32(const void* p) {
  unsigned r;
  asm volatile("global_load_dword %0, %1, off sc0 sc1\n\ts_waitcnt vmcnt(0)"
               : "=v"(r) : "v"(p) : "memory");
  return r;
}
__device__ __forceinline__ half8 coh_load_h8(const void* p) {
  half8 r;
  asm volatile("global_load_dwordx4 %0, %1, off sc0 sc1" : "=v"(r) : "v"(p));
  return r;
}
// drain all outstanding vmem; ties the 16 y-frags so dependent MFMAs can't hoist
__device__ __forceinline__ void ysync16(half8* y) {
  asm volatile("s_waitcnt vmcnt(0)"
               : "+v"(y[0]), "+v"(y[1]), "+v"(y[2]), "+v"(y[3]),
                 "+v"(y[4]), "+v"(y[5]), "+v"(y[6]), "+v"(y[7]),
                 "+v"(y[8]), "+v"(y[9]), "+v"(y[10]), "+v"(y[11]),
                 "+v"(y[12]), "+v"(y[13]), "+v"(y[14]), "+v"(y[15])
               :: "memory");
}
// zero-instruction volatile tie: pins the 16 y-frags' definition point so
// consuming MFMAs cannot be scheduled above it (no extra waitcnt).
__device__ __forceinline__ void ytie16(half8* y) {
  asm volatile(""
               : "+v"(y[0]), "+v"(y[1]), "+v"(y[2]), "+v"(y[3]),
                 "+v"(y[4]), "+v"(y[5]), "+v"(y[6]), "+v"(y[7]),
                 "+v"(y[8]), "+v"(y[9]), "+v"(y[10]), "+v"(y[11]),
                 "+v"(y[12]), "+v"(y[13]), "+v"(y[14]), "+v"(y[15])
               ::);
}

// ---- leaf-direct grid barrier. 256 blocks = 32 leaves x 8 blocks.
// Arrive: drain own stores, block-sync, one fire-and-forget leaf atomic.
__device__ __forceinline__ void bar_arrive(unsigned* leaf, int tid, int bx) {
  asm volatile("s_waitcnt vmcnt(0)" ::: "memory");   // drain our coherent stores
  __syncthreads();
  if (tid == 0)
    __hip_atomic_fetch_add(&leaf[(bx >> 3) << 5], 1u,
                           __ATOMIC_RELAXED, __HIP_MEMORY_SCOPE_AGENT);
}
// Wait (per-wave): lanes 0..15 poll the 16 leaf counters covering this
// wave's K-slice. Poll decay: lanes latch success and stop re-loading.
// s_sleep(2) backoff after each failed ballot cuts steady-state poll traffic.
__device__ __forceinline__ void wave_wait(unsigned* leaf, int lane, int kb0, unsigned ep) {
  const unsigned tgt = ep * 8u;
  const unsigned* p = &leaf[(unsigned)(kb0 + (lane & 15)) << 5];
  bool myok = false;
  for (;;) {
    if (!myok) myok = (coh_load32(p) >= tgt);
    if (__all((int)myok)) break;
    __builtin_amdgcn_s_sleep(2);
  }
}

// ---- LDS tile fill: pack 16 rows (row map per 4-row gate group, -1 = zeros)
// into MFMA A-fragment order: elem((kb,quad,m),j) = ((kb*64 + quad*16 + m)*8 + j)
__device__ __forceinline__ void fill_tile_f32(char* smem, int off, const float* __restrict__ src,
                                              int u0, int g0, int g1, int g2, int g3, int tid) {
  const int w = tid >> 6, lane = tid & 63;
  int gsel[4] = {g0, g1, g2, g3};
#pragma unroll
  for (int mm = 0; mm < 2; ++mm) {
    const int m = w + mm * 8;
    const int g = gsel[m >> 2];
    const long srow = (g < 0) ? -1 : (long)g * DM + u0 + (m & 3);
#pragma unroll
    for (int p = 0; p < 4; ++p) {
      const int k = p * 256 + lane * 4;
      half4f hv;
      if (srow >= 0) {
        float4 v = *(const float4*)(src + srow * DM + k);
        hv = (half4f){(_Float16)v.x, (_Float16)v.y, (_Float16)v.z, (_Float16)v.w};
      } else {
        hv = (half4f){(_Float16)0.f, (_Float16)0.f, (_Float16)0.f, (_Float16)0.f};
      }
      const int kb = k >> 5, q = (k >> 3) & 3;
      const int elem = (kb * 64 + q * 16 + m) * 8 + (k & 7);
      *(half4f*)(smem + off + elem * 2) = hv;
    }
  }
}

__device__ __forceinline__ void fill_tile_f16(char* smem, int off, const _Float16* __restrict__ src,
                                              int u0, int g0, int g1, int g2, int g3, int tid) {
  const int w = tid >> 6, lane = tid & 63;
  int gsel[4] = {g0, g1, g2, g3};
#pragma unroll
  for (int mm = 0; mm < 2; ++mm) {
    const int m = w + mm * 8;
    const int g = gsel[m >> 2];
    const long srow = (g < 0) ? -1 : (long)g * DM + u0 + (m & 3);
#pragma unroll
    for (int p = 0; p < 4; ++p) {
      const int k = p * 256 + lane * 4;
      half4f hv;
      if (srow >= 0) hv = *(const half4f*)(src + srow * DM + k);
      else hv = (half4f){(_Float16)0.f, (_Float16)0.f, (_Float16)0.f, (_Float16)0.f};
      const int kb = k >> 5, q = (k >> 3) & 3;
      const int elem = (kb * 64 + q * 16 + m) * 8 + (k & 7);
      *(half4f*)(smem + off + elem * 2) = hv;
    }
  }
}

// small per-CU constants: x-side weight slice + fused biases
__device__ __forceinline__ void fill_small(char* smem, int u0, int tid,
    const float* __restrict__ Wih0, const float* __restrict__ bihA, const float* __restrict__ bhhA,
    const float* __restrict__ bih1, const float* __restrict__ bhh1, const float* __restrict__ bf0) {
  if (tid < 132) {
    const int rr = tid / 11, c = tid - rr * 11;
    const int g = rr >> 2, ul = rr & 3;
    ((float*)(smem + L_XW))[(g * 4 + ul) * 12 + c] = Wih0[(g * DM + u0 + ul) * 11 + c];
  }
  if (tid < 4) {
    const int u = u0 + tid;
    float* bA = (float*)(smem + L_BA);
    bA[tid] = bihA[u] + bhhA[u];
    bA[4 + tid] = bihA[DM + u] + bhhA[DM + u];
    bA[8 + tid] = bhhA[2 * DM + u];
    bA[12 + tid] = bihA[2 * DM + u];
    float* bB = (float*)(smem + L_BB);
    bB[tid] = bih1[u] + bhh1[u];
    bB[4 + tid] = bih1[DM + u] + bhh1[DM + u];
    bB[8 + tid] = bhh1[2 * DM + u];
    bB[12 + tid] = bih1[2 * DM + u];
    if (bf0) {
      float* bAa = (float*)(smem + L_BAA);
      bAa[tid] = bf0[u] + bhhA[u];
      bAa[4 + tid] = bf0[DM + u] + bhhA[DM + u];
      bAa[8 + tid] = bhhA[2 * DM + u];
      bAa[12 + tid] = bf0[2 * DM + u];
    }
  }
}

#define MFMA16 __builtin_amdgcn_mfma_f32_16x16x32_f16
#define ZERO4 ((f32x4){0.f, 0.f, 0.f, 0.f})

// ---- batch-issue 16 coherent y-fragment loads for this wave's (bs, kb0)
__device__ __forceinline__ void yload(half8* y, const _Float16* src, int kb0, int lane, int bs) {
  const half8* B = (const half8*)src + ((lane >> 4) << 6) + bs + (lane & 15);
#pragma unroll
  for (int i = 0; i < 16; ++i)
    y[i] = coh_load_h8(B + ((size_t)(kb0 + i) << 8));
}

// ---- 16-MFMA pass of one LDS tile against register-held y-frags
__device__ __forceinline__ f32x4 gemm_reg(const char* smem, int toff, int kb0, int lane,
                                          const half8* y, f32x4 seed) {
  const half8* T = (const half8*)(smem + toff);
  f32x4 aE = seed, aO = ZERO4;
#pragma unroll
  for (int i = 0; i < 16; i += 2) {
    aE = MFMA16(T[((kb0 + i) << 6) + lane], y[i], aE, 0, 0, 0);
    aO = MFMA16(T[((kb0 + i + 1) << 6) + lane], y[i + 1], aO, 0, 0, 0);
  }
  return aE + aO;
}

// ---- write acc to a TR region (all 8 waves)
__device__ __forceinline__ void tr_store(char* smem, int trOff, int w, int lane, f32x4 acc) {
  float* tr = (float*)(smem + trOff) + (w << 8);
  const int quad = lane >> 4, col = lane & 15;
  tr[(quad * 4 + 0) * 16 + col] = acc[0];
  tr[(quad * 4 + 1) * 16 + col] = acc[1];
  tr[(quad * 4 + 2) * 16 + col] = acc[2];
  tr[(quad * 4 + 3) * 16 + col] = acc[3];
}

// ---- x-side GEMV precompute. xmode 1: 7 inputs + 4 marks; 2: marks only.
__device__ __forceinline__ void x_pre(const char* smem, int xmode,
    const float* __restrict__ xin, const float* __restrict__ xmk,
    int t, int seqT, int b, int ul, float& xr, float& xz, float& xn) {
  const float* xw = (const float*)(smem + L_XW);
  xr = 0.f; xz = 0.f; xn = 0.f;
  if (xmode == 1) {
    const float* xp = xin + (size_t)(b * seqT + t) * 7;
#pragma unroll
    for (int c = 0; c < 7; ++c) {
      float v = xp[c];
      xr = fmaf(xw[ul * 12 + c], v, xr);
      xz = fmaf(xw[(4 + ul) * 12 + c], v, xz);
      xn = fmaf(xw[(8 + ul) * 12 + c], v, xn);
    }
  }
  const float* mp = xmk + (size_t)(b * seqT + t) * 4;
#pragma unroll
  for (int m = 0; m < 4; ++m) {
    float v = mp[m];
    xr = fmaf(xw[ul * 12 + 7 + m], v, xr);
    xz = fmaf(xw[(4 + ul) * 12 + 7 + m], v, xz);
    xn = fmaf(xw[(8 + ul) * 12 + 7 + m], v, xn);
  }
}

// ---- gate epilogue for one wave group (wb=0: waves0-3, wb=4: waves4-7).
__device__ __forceinline__ void epi(char* smem, int trOff, int stOff, int wb,
                                    int biasOff, float pxr, float pxz, float pxn,
                                    int tid, float& hprev) {
  const int lane = tid & 63, w = tid >> 6;
  const int bg = w - wb;
  const int col = lane & 15, ul = lane >> 4;
  const float* t0 = (const float*)(smem + trOff) + (bg << 8);
  const float* t1 = t0 + (4 << 8);
  const int b = (bg << 4) + col;
  float vr  = t0[ul * 16 + col]        + t1[ul * 16 + col];
  float vz  = t0[(4 + ul) * 16 + col]  + t1[(4 + ul) * 16 + col];
  float vnh = t0[(8 + ul) * 16 + col]  + t1[(8 + ul) * 16 + col];
  float vni = t0[(12 + ul) * 16 + col] + t1[(12 + ul) * 16 + col];
  const float* bias = (const float*)(smem + biasOff);
  float rg = sigm(vr + bias[ul] + pxr);
  float zg = sigm(vz + bias[4 + ul] + pxz);
  float ng = tanhf((vni + bias[12 + ul] + pxn) + rg * (vnh + bias[8 + ul]));
  float hn = ng + zg * (hprev - ng);
  hprev = hn;
  ((_Float16*)(smem + stOff))[b * 4 + ul] = (_Float16)hn;
}

// ---- coherent 8B store of a 512B stage region (one wave: i = 0..63)
__device__ __forceinline__ void st8(_Float16* dst, int u0, int i, const char* stage) {
  unsigned long long v = *(const unsigned long long*)(stage + i * 8);
  char* gp = (char*)dst + (((size_t)(u0 >> 3)) * 64 + i) * 16 + (size_t)(u0 & 7) * 2;
  coh_store64(gp, v);
}

// ---- prep: Wf = dW_ih0[:, :7] @ out_W (f16), bf0 = db_ih0 + dW_ih0[:, :7] @ out_b
__global__ __launch_bounds__(256) void prep_wf(const float* __restrict__ dWih0,
                                               const float* __restrict__ dbih0,
                                               const float* __restrict__ outW,
                                               const float* __restrict__ outb,
                                               char* __restrict__ ws) {
  const int j = blockIdx.x;
  _Float16* wf = (_Float16*)(ws + OFF_WF);
  float* bf0 = (float*)(ws + OFF_BF0);
  float wrow[7];
#pragma unroll
  for (int c = 0; c < 7; ++c) wrow[c] = dWih0[j * 11 + c];
#pragma unroll
  for (int p = 0; p < 4; ++p) {
    const int k = p * 256 + threadIdx.x;
    float acc = 0.f;
#pragma unroll
    for (int c = 0; c < 7; ++c) acc = fmaf(wrow[c], outW[c * DM + k], acc);
    wf[(size_t)j * DM + k] = (_Float16)acc;
  }
  if (threadIdx.x == 0) {
    float bb = dbih0[j];
#pragma unroll
    for (int c = 0; c < 7; ++c) bb = fmaf(wrow[c], outb[c], bb);
    bf0[j] = bb;
  }
}

__global__ __launch_bounds__(512) void gru_persist(
    const float* __restrict__ xe,  const float* __restrict__ xme,
    const float* __restrict__ xd,  const float* __restrict__ xmd,
    const float* __restrict__ eWih0, const float* __restrict__ eWhh0,
    const float* __restrict__ ebih0, const float* __restrict__ ebhh0,
    const float* __restrict__ eWih1, const float* __restrict__ eWhh1,
    const float* __restrict__ ebih1, const float* __restrict__ ebhh1,
    const float* __restrict__ dWih0, const float* __restrict__ dWhh0,
    const float* __restrict__ dbih0, const float* __restrict__ dbhh0,
    const float* __restrict__ dWih1, const float* __restrict__ dWhh1,
    const float* __restrict__ dbih1, const float* __restrict__ dbhh1,
    char* __restrict__ ws) {
  extern __shared__ char smem[];
  const int tid = threadIdx.x, bx = blockIdx.x;
  const int lane = tid & 63;
  const int w = tid >> 6;
  const int bg = w & 3, kslice = w >> 2;
  const int bs = bg << 4, kb0 = kslice << 4;
  const int u0 = bx << 2;
  const int bA = ((w & 3) << 4) + (lane & 15);   // epilogue batch coord
  const int ulA = lane >> 4;                      // epilogue unit coord

  unsigned* leaf = (unsigned*)ws;
  _Float16* h0p[2] = {(_Float16*)(ws + OFF_H0P0), (_Float16*)(ws + OFF_H0P0 + HB)};
  _Float16* eh1[2] = {(_Float16*)(ws + OFF_EH10), (_Float16*)(ws + OFF_EH10 + HB)};
  _Float16* dh1 = (_Float16*)(ws + OFF_DH1);
  const _Float16* wf = (const _Float16*)(ws + OFF_WF);
  const float* bf0 = (const float*)(ws + OFF_BF0);

  half8 y0[16], y1[16];
  f32x4 carryI = ZERO4, carryA = ZERO4, carryB = ZERO4;
  float pxr = 0.f, pxz = 0.f, pxn = 0.f;
  float hA = 0.f, hB = 0.f;
  unsigned ep = 0;

  // ---------- encoder weights -> LDS ----------
  fill_tile_f32(smem, L_TA0, eWhh0, u0, 0, 1, 2, -1, tid);   // gh0: r,z,nh | zeros
  fill_tile_f32(smem, L_TB0, eWih1, u0, 0, 1, -1, 2, tid);   // gi1: r,z | zeros | ni
  fill_tile_f32(smem, L_TB1, eWhh1, u0, 0, 1, 2, -1, tid);   // gh1: r,z,nh | zeros
  fill_small(smem, u0, tid, eWih0, ebih0, ebhh0, ebih1, ebhh1, nullptr);
  __syncthreads();
  if (w < 4) x_pre(smem, 1, xe, xme, 0, TENC, bA, ulA, pxr, pxz, pxn);

  // ---------- encoder: interval t = L0(t) + L1(t-2) ----------
  for (int t = 0; t < TENC; ++t) {
    wave_wait(leaf, lane, kb0, ep);
    yload(y0, h0p[t & 1], kb0, lane, bs);                       // h0(t-1)
    if (t >= 2) yload(y1, eh1[(t - 3) & 1], kb0, lane, bs);     // h1(t-3)
    ysync16(y0);
    if (t >= 2) ytie16(y1);
    f32x4 aA = gemm_reg(smem, L_TA0, kb0, lane, y0, ZERO4);     // gh0·h0(t-1)
    tr_store(smem, L_TRA, w, lane, aA);
    if (t >= 2) {
      f32x4 aB = gemm_reg(smem, L_TB1, kb0, lane, y1, carryI);  // + gi1·h0(t-2)
      tr_store(smem, L_TRB, w, lane, aB);
    }
    __syncthreads();
    if (w < 4) epi(smem, L_TRA, L_HSTA, 0, L_BA, pxr, pxz, pxn, tid, hA);
    else if (t >= 2) epi(smem, L_TRB, L_HSTB, 4, L_BB, 0.f, 0.f, 0.f, tid, hB);
    __syncthreads();
    if (tid < 64) st8(h0p[(t & 1) ^ 1], u0, tid, smem + L_HSTA);
    else if (t >= 2 && tid < 128) st8(eh1[t & 1], u0, tid - 64, smem + L_HSTB);
    bar_arrive(leaf, tid, bx); ++ep;
    carryI = gemm_reg(smem, L_TB0, kb0, lane, y0, ZERO4);       // gi1·h0(t-1)
    if (w < 4 && t + 1 < TENC) x_pre(smem, 1, xe, xme, t + 1, TENC, bA, ulA, pxr, pxz, pxn);
  }
  // drain E1: L1(190) -> eh1[0]
  {
    wave_wait(leaf, lane, kb0, ep);
    yload(y0, h0p[0], kb0, lane, bs);                           // h0(191)
    yload(y1, eh1[1], kb0, lane, bs);                           // h1(189)
    ysync16(y0);
    ytie16(y1);
    f32x4 aB = gemm_reg(smem, L_TB1, kb0, lane, y1, carryI);
    tr_store(smem, L_TRB, w, lane, aB);
    __syncthreads();
    if (w >= 4) epi(smem, L_TRB, L_HSTB, 4, L_BB, 0.f, 0.f, 0.f, tid, hB);
    __syncthreads();
    if (tid >= 64 && tid < 128) st8(eh1[0], u0, tid - 64, smem + L_HSTB);
    bar_arrive(leaf, tid, bx); ++ep;
    carryI = gemm_reg(smem, L_TB0, kb0, lane, y0, ZERO4);       // gi1·h0(191)
  }
  // drain E2: L1(191) -> dh1[0]; then swap to decoder weights
  {
    wave_wait(leaf, lane, kb0, ep);
    yload(y1, eh1[0], kb0, lane, bs);                           // h1(190)
    ysync16(y1);
    f32x4 aB = gemm_reg(smem, L_TB1, kb0, lane, y1, carryI);
    tr_store(smem, L_TRB, w, lane, aB);
    __syncthreads();
    if (w >= 4) epi(smem, L_TRB, L_HSTB, 4, L_BB, 0.f, 0.f, 0.f, tid, hB);
    __syncthreads();
    if (tid >= 64 && tid < 128) st8(dh1, u0, tid - 64, smem + L_HSTB);
    bar_arrive(leaf, tid, bx); ++ep;
    // decoder weights -> LDS (read-only globals; our own compute done)
    fill_tile_f32(smem, L_TA0, dWhh0, u0, 0, 1, 2, -1, tid);
    fill_tile_f16(smem, L_TA1, wf,    u0, 0, 1, -1, 2, tid);
    fill_tile_f32(smem, L_TB0, dWih1, u0, 0, 1, -1, 2, tid);
    fill_tile_f32(smem, L_TB1, dWhh1, u0, 0, 1, 2, -1, tid);
    fill_small(smem, u0, tid, dWih0, dbih0, dbhh0, dbih1, dbhh1, bf0);
    __syncthreads();
    if (w < 4) x_pre(smem, 1, xd, xmd, 0, TDEC, bA, ulA, pxr, pxz, pxn);
  }

  // ---------- label: interval d = L0d(d) + L1d(d-2) ----------
  for (int d = 0; d < LBL; ++d) {
    wave_wait(leaf, lane, kb0, ep);
    yload(y0, h0p[d & 1], kb0, lane, bs);                       // h0 step 192+d-1
    if (d >= 2) yload(y1, dh1 + (size_t)(d - 2) * HE, kb0, lane, bs);  // h1d(d-3)
    ysync16(y0);
    if (d >= 2) ytie16(y1);
    f32x4 aA = gemm_reg(smem, L_TA0, kb0, lane, y0, ZERO4);
    tr_store(smem, L_TRA, w, lane, aA);
    if (d >= 2) {
      f32x4 aB = gemm_reg(smem, L_TB1, kb0, lane, y1, carryI);
      tr_store(smem, L_TRB, w, lane, aB);
    }
    __syncthreads();
    if (w < 4) epi(smem, L_TRA, L_HSTA, 0, L_BA, pxr, pxz, pxn, tid, hA);
    else if (d >= 2) epi(smem, L_TRB, L_HSTB, 4, L_BB, 0.f, 0.f, 0.f, tid, hB);
    __syncthreads();
    if (tid < 64) st8(h0p[(d & 1) ^ 1], u0, tid, smem + L_HSTA);
    else if (d >= 2 && tid < 128) st8(dh1 + (size_t)(d - 1) * HE, u0, tid - 64, smem + L_HSTB);
    bar_arrive(leaf, tid, bx); ++ep;
    carryI = gemm_reg(smem, L_TB0, kb0, lane, y0, ZERO4);
    if (w < 4 && d + 1 < LBL) x_pre(smem, 1, xd, xmd, d + 1, TDEC, bA, ulA, pxr, pxz, pxn);
  }
  // drain D1: L1d(46) -> dh1[47]; seed carryI(gi1·h0d(47)) + carryA(gh0·h0d(47))
  {
    wave_wait(leaf, lane, kb0, ep);
    yload(y0, h0p[0], kb0, lane, bs);                           // h0d(47)
    yload(y1, dh1 + (size_t)46 * HE, kb0, lane, bs);            // h1d(45)
    ysync16(y0);
    ytie16(y1);
    f32x4 aB = gemm_reg(smem, L_TB1, kb0, lane, y1, carryI);
    tr_store(smem, L_TRB, w, lane, aB);
    __syncthreads();
    if (w >= 4) epi(smem, L_TRB, L_HSTB, 4, L_BB, 0.f, 0.f, 0.f, tid, hB);
    __syncthreads();
    if (tid >= 64 && tid < 128) st8(dh1 + (size_t)47 * HE, u0, tid - 64, smem + L_HSTB);
    bar_arrive(leaf, tid, bx); ++ep;
    carryI = gemm_reg(smem, L_TB0, kb0, lane, y0, ZERO4);
    carryA = gemm_reg(smem, L_TA0, kb0, lane, y0, ZERO4);
  }
  // drain D2: L1d(47) -> dh1[48]
  {
    wave_wait(leaf, lane, kb0, ep);
    yload(y1, dh1 + (size_t)47 * HE, kb0, lane, bs);
    ysync16(y1);
    f32x4 aB = gemm_reg(smem, L_TB1, kb0, lane, y1, carryI);
    tr_store(smem, L_TRB, w, lane, aB);
    __syncthreads();
    if (w >= 4) epi(smem, L_TRB, L_HSTB, 4, L_BB, 0.f, 0.f, 0.f, tid, hB);
    __syncthreads();
    if (tid >= 64 && tid < 128) st8(dh1 + (size_t)48 * HE, u0, tid - 64, smem + L_HSTB);
    bar_arrive(leaf, tid, bx); ++ep;
    if (w < 4) x_pre(smem, 2, nullptr, xmd, LBL, TDEC, bA, ulA, pxr, pxz, pxn);
  }

  // ---------- autoregressive region: s = 48..215, A/B intervals ----------
  for (int s = LBL; s < TDEC; ++s) {
    // A(s): h0(s) = f(carryA + Wf·h1(s-1) + marks); post: carryB = gh1·h1(s-1)
    wave_wait(leaf, lane, kb0, ep);
    yload(y1, dh1 + (size_t)s * HE, kb0, lane, bs);
    ysync16(y1);
    f32x4 aA = gemm_reg(smem, L_TA1, kb0, lane, y1, carryA);
    tr_store(smem, L_TRA, w, lane, aA);
    __syncthreads();
    if (w < 4) epi(smem, L_TRA, L_HSTA, 0, L_BAA, pxr, pxz, pxn, tid, hA);
    __syncthreads();
    if (tid < 64) st8(h0p[(s & 1) ^ 1], u0, tid, smem + L_HSTA);
    bar_arrive(leaf, tid, bx); ++ep;
    carryB = gemm_reg(smem, L_TB1, kb0, lane, y1, ZERO4);
    // B(s): h1(s) = f(carryB + gi1·h0(s)); post: carryA = gh0·h0(s), x_pre(s+1)
    wave_wait(leaf, lane, kb0, ep);
    yload(y0, h0p[(s & 1) ^ 1], kb0, lane, bs);
    ysync16(y0);
    f32x4 aB = gemm_reg(smem, L_TB0, kb0, lane, y0, carryB);
    tr_store(smem, L_TRB, w, lane, aB);
    __syncthreads();
    if (w >= 4) epi(smem, L_TRB, L_HSTB, 4, L_BB, 0.f, 0.f, 0.f, tid, hB);
    __syncthreads();
    if (tid >= 64 && tid < 128) st8(dh1 + (size_t)(s + 1) * HE, u0, tid - 64, smem + L_HSTB);
    bar_arrive(leaf, tid, bx); ++ep;
    carryA = gemm_reg(smem, L_TA0, kb0, lane, y0, ZERO4);
    if (w < 4 && s + 1 < TDEC) x_pre(smem, 2, nullptr, xmd, s + 1, TDEC, bA, ulA, pxr, pxz, pxn);
  }
}

// ---- epilogue projection: preds from stored h1 history (packed f16)
__global__ __launch_bounds__(64) void proj_kernel(const char* __restrict__ ws,
                                                  const float* __restrict__ outW,
                                                  const float* __restrict__ outb,
                                                  float* __restrict__ out) {
  const int ti = blockIdx.x / 7, c = blockIdx.x % 7;
  const _Float16* h = (const _Float16*)(ws + OFF_DH1) + (size_t)(LBL + 1 + ti) * HE;
  const int b = threadIdx.x;
  const float* wrow = outW + c * DM;
  float acc = outb[c];
#pragma unroll 4
  for (int k8 = 0; k8 < 128; ++k8) {
    const half8 hv = *(const half8*)(h + ((size_t)k8 * 64 + b) * 8);
    const float* wp = wrow + k8 * 8;
#pragma unroll
    for (int j = 0; j < 8; ++j) acc = fmaf((float)hv[j], wp[j], acc);
  }
  out[(size_t)b * (NPRED * 7) + ti * 7 + c] = acc;
}

extern "C" void kernel_launch(void* const* d_in, const int* in_sizes, int n_in,
                              void* d_out, int out_size, void* d_ws, size_t ws_size,
                              hipStream_t stream) {
  (void)in_sizes; (void)n_in; (void)out_size; (void)ws_size;
  const float* xe    = (const float*)d_in[0];
  const float* xme   = (const float*)d_in[1];
  const float* xd    = (const float*)d_in[2];
  const float* xmd   = (const float*)d_in[3];
  const float* eWih0 = (const float*)d_in[4];
  const float* eWhh0 = (const float*)d_in[5];
  const float* ebih0 = (const float*)d_in[6];
  const float* ebhh0 = (const float*)d_in[7];
  const float* eWih1 = (const float*)d_in[8];
  const float* eWhh1 = (const float*)d_in[9];
  const float* ebih1 = (const float*)d_in[10];
  const float* ebhh1 = (const float*)d_in[11];
  const float* dWih0 = (const float*)d_in[12];
  const float* dWhh0 = (const float*)d_in[13];
  const float* dbih0 = (const float*)d_in[14];
  const float* dbhh0 = (const float*)d_in[15];
  const float* dWih1 = (const float*)d_in[16];
  const float* dWhh1 = (const float*)d_in[17];
  const float* dbih1 = (const float*)d_in[18];
  const float* dbhh1 = (const float*)d_in[19];
  const float* outW  = (const float*)d_in[20];
  const float* outb  = (const float*)d_in[21];
  char* ws = (char*)d_ws;

  hipFuncSetAttribute(reinterpret_cast<const void*>(gru_persist),
                      hipFuncAttributeMaxDynamicSharedMemorySize, SMEM_BYTES);

  // zero: barrier counters + h0pack slot0 + encoder h1pack BOTH slots
  hipMemsetAsync(ws, 0, OFF_H0P0 + HB, stream);
  hipMemsetAsync(ws + OFF_EH10, 0, 2 * HB, stream);

  prep_wf<<<3072, 256, 0, stream>>>(dWih0, dbih0, outW, outb, ws);
  gru_persist<<<256, 512, SMEM_BYTES, stream>>>(xe, xme, xd, xmd,
                                                eWih0, eWhh0, ebih0, ebhh0,
                                                eWih1, eWhh1, ebih1, ebhh1,
                                                dWih0, dWhh0, dbih0, dbhh0,
                                                dWih1, dWhh1, dbih1, dbhh1, ws);
  proj_kernel<<<NPRED * 7, 64, 0, stream>>>(ws, outW, outb, (float*)d_out);
}